// Round 2
// baseline (1609.491 us; speedup 1.0000x reference)
//
#include <hip/hip_runtime.h>
#include <hip/hip_bf16.h>

#define HID 64
#define G3  192
#define NBATCH 2048
#define NT  512
#define DIN 7
#define SPB 16      // samples per block
#define CTC 64      // time chunk staged in LDS
#define FSTR 132    // f16 stride for hidden-state frag buffers (128 + 4 pad)

typedef _Float16 half4 __attribute__((ext_vector_type(4)));
typedef float    f32x4 __attribute__((ext_vector_type(4)));

__device__ __forceinline__ float sigm(float v) { return 1.0f / (1.0f + __expf(-v)); }
__device__ __forceinline__ float tanh_f(float v) {
  v = fminf(fmaxf(v, -15.0f), 15.0f);
  float e = __expf(-2.0f * v);
  return (1.0f - e) / (1.0f + e);
}

// One persistent block per 16 samples; both GRU layers fused; h kept as f16 hi/lo
// pair (effective fp32 precision) feeding v_mfma_f32_16x16x16_f16 with K=128.
// All inputs are float32 (harness pushes f32; reference is jnp.float32).
__global__ __launch_bounds__(256, 1) void gru_fused(
    const float* __restrict__ x,     // [B][T][7]
    const float* __restrict__ Wih0,  // [192][7]
    const float* __restrict__ Whh0,  // [192][64]
    const float* __restrict__ bih0,  // [192]
    const float* __restrict__ bhh0,  // [192]
    const float* __restrict__ Wih1,  // [192][64]
    const float* __restrict__ Whh1,  // [192][64]
    const float* __restrict__ bih1,  // [192]
    const float* __restrict__ bhh1,  // [192]
    const float* __restrict__ fcW,   // [64]
    const float* __restrict__ fcb,   // [1]
    float* __restrict__ out)         // [2048]
{
  __shared__ __align__(16) _Float16 xbuf[SPB * CTC * 8];  // 16 KB, x chunk as f16, padded to 8
  __shared__ __align__(16) float    xg[SPB * G3];         // 12 KB  input-gate pre-acts
  __shared__ __align__(16) float    hg[SPB * G3];         // 12 KB  hidden-gate pre-acts
  __shared__ __align__(16) _Float16 F0[SPB * FSTR];       // layer0 h as [hi(64)|lo(64)] f16
  __shared__ __align__(16) _Float16 F1[SPB * FSTR];       // layer1 h
  __shared__ float bias[4 * G3];                          // bih0,bhh0,bih1,bhh1
  __shared__ float fcWs[HID + 1];

  const int tid  = threadIdx.x;
  const int lane = tid & 63;
  const int wave = tid >> 6;
  const int col  = lane & 15;   // MFMA: A-row (sample) / B-col (gate-in-tile)
  const int quad = lane >> 4;   // MFMA: k sub-block
  const int s0   = blockIdx.x * SPB;

  if (tid < G3) {
    bias[tid]           = bih0[tid];
    bias[G3 + tid]      = bhh0[tid];
    bias[2 * G3 + tid]  = bih1[tid];
    bias[3 * G3 + tid]  = bhh1[tid];
  }
  if (tid < HID)  fcWs[tid] = fcW[tid];
  if (tid == 64)  fcWs[HID] = fcb[0];
  for (int i = tid; i < SPB * FSTR; i += 256) { F0[i] = (_Float16)0; F1[i] = (_Float16)0; }

  // ---- preload all weight B-fragments into registers (loop-invariant) ----
  // B[k][n] = W[g = ntile*16 + (l&15)][k], k = kt*16 + 4*quad + i
  half4 wih0[3], whh0[3][4], wih1[3][4], whh1[3][4];
#pragma unroll
  for (int nt = 0; nt < 3; ++nt) {
    const int g = (wave * 3 + nt) * 16 + col;
#pragma unroll
    for (int kt = 0; kt < 4; ++kt) {
      const int k0 = kt * 16 + quad * 4;
      half4 a, b, c;
#pragma unroll
      for (int i = 0; i < 4; ++i) {
        a[i] = (_Float16)Whh0[g * HID + k0 + i];
        b[i] = (_Float16)Wih1[g * HID + k0 + i];
        c[i] = (_Float16)Whh1[g * HID + k0 + i];
      }
      whh0[nt][kt] = a; wih1[nt][kt] = b; whh1[nt][kt] = c;
    }
    half4 w0;
#pragma unroll
    for (int i = 0; i < 4; ++i) {
      const int k = quad * 4 + i;
      w0[i] = (k < DIN) ? (_Float16)Wih0[g * DIN + k] : (_Float16)0;
    }
    wih0[nt] = w0;
  }

  const int jj = tid & 63;  // gate-math: h index
  const int sb = tid >> 6;  // gate-math: base sample

  for (int tc = 0; tc < NT / CTC; ++tc) {
    __syncthreads();  // xbuf free (covers init before first use too)
    // ---- stage 64-step x chunk, f32 -> f16, pad dim 7 -> 8 ----
    for (int e = tid; e < SPB * CTC * DIN; e += 256) {
      const int s   = e / (CTC * DIN);
      const int rem = e - s * (CTC * DIN);
      const int t   = rem / DIN;
      const int d   = rem - t * DIN;
      const float v = x[((size_t)(s0 + s) * NT + (size_t)tc * CTC + t) * DIN + d];
      xbuf[(s * CTC + t) * 8 + d] = (_Float16)v;
    }
    for (int e = tid; e < SPB * CTC; e += 256) xbuf[e * 8 + 7] = (_Float16)0;
    __syncthreads();

    for (int ti = 0; ti < CTC; ++ti) {
      // ======== phase 1: layer0  xg = x@Wih0^T,  hg = h0@Whh0^T ========
      f32x4 ax[3] = {{0,0,0,0},{0,0,0,0},{0,0,0,0}};
      f32x4 ah[3] = {{0,0,0,0},{0,0,0,0},{0,0,0,0}};
      {
        half4 a0 = {0, 0, 0, 0};
        if (quad < 2) a0 = *(const half4*)&xbuf[(col * CTC + ti) * 8 + quad * 4];
        ax[0] = __builtin_amdgcn_mfma_f32_16x16x16f16(a0, wih0[0], ax[0], 0, 0, 0);
        ax[1] = __builtin_amdgcn_mfma_f32_16x16x16f16(a0, wih0[1], ax[1], 0, 0, 0);
        ax[2] = __builtin_amdgcn_mfma_f32_16x16x16f16(a0, wih0[2], ax[2], 0, 0, 0);
      }
#pragma unroll
      for (int kt = 0; kt < 8; ++kt) {  // K=128: h0 hi (kt 0-3) + lo (kt 4-7), W repeated
        half4 a = *(const half4*)&F0[col * FSTR + kt * 16 + quad * 4];
        ah[0] = __builtin_amdgcn_mfma_f32_16x16x16f16(a, whh0[0][kt & 3], ah[0], 0, 0, 0);
        ah[1] = __builtin_amdgcn_mfma_f32_16x16x16f16(a, whh0[1][kt & 3], ah[1], 0, 0, 0);
        ah[2] = __builtin_amdgcn_mfma_f32_16x16x16f16(a, whh0[2][kt & 3], ah[2], 0, 0, 0);
      }
#pragma unroll
      for (int nt = 0; nt < 3; ++nt) {
        const int g = (wave * 3 + nt) * 16 + col;
#pragma unroll
        for (int i = 0; i < 4; ++i) {
          const int m = quad * 4 + i;
          xg[m * G3 + g] = ax[nt][i];
          hg[m * G3 + g] = ah[nt][i];
        }
      }
      __syncthreads();

      // ======== phase 2: layer0 gate math, write new h0 (hi/lo) ========
#pragma unroll
      for (int r = 0; r < 4; ++r) {
        const int s = sb + r * 4;
        const float hprev = (float)F0[s * FSTR + jj] + (float)F0[s * FSTR + 64 + jj];
        const float xr = xg[s * G3 + jj],       hr = hg[s * G3 + jj];
        const float xz = xg[s * G3 + 64 + jj],  hz = hg[s * G3 + 64 + jj];
        const float xn = xg[s * G3 + 128 + jj], hn = hg[s * G3 + 128 + jj];
        const float rg = sigm(xr + hr + bias[jj] + bias[G3 + jj]);
        const float zg = sigm(xz + hz + bias[64 + jj] + bias[G3 + 64 + jj]);
        const float ng = tanh_f(xn + bias[128 + jj] + rg * (hn + bias[G3 + 128 + jj]));
        const float hnew = (1.0f - zg) * ng + zg * hprev;
        const _Float16 hi = (_Float16)hnew;
        const _Float16 lo = (_Float16)(hnew - (float)hi);
        F0[s * FSTR + jj] = hi;
        F0[s * FSTR + 64 + jj] = lo;
      }
      __syncthreads();

      // ======== phase 3: layer1  xg = h0new@Wih1^T,  hg = h1@Whh1^T ========
#pragma unroll
      for (int nt = 0; nt < 3; ++nt) { ax[nt] = (f32x4){0,0,0,0}; ah[nt] = (f32x4){0,0,0,0}; }
#pragma unroll
      for (int kt = 0; kt < 8; ++kt) {
        half4 a = *(const half4*)&F0[col * FSTR + kt * 16 + quad * 4];
        ax[0] = __builtin_amdgcn_mfma_f32_16x16x16f16(a, wih1[0][kt & 3], ax[0], 0, 0, 0);
        ax[1] = __builtin_amdgcn_mfma_f32_16x16x16f16(a, wih1[1][kt & 3], ax[1], 0, 0, 0);
        ax[2] = __builtin_amdgcn_mfma_f32_16x16x16f16(a, wih1[2][kt & 3], ax[2], 0, 0, 0);
      }
#pragma unroll
      for (int kt = 0; kt < 8; ++kt) {
        half4 a = *(const half4*)&F1[col * FSTR + kt * 16 + quad * 4];
        ah[0] = __builtin_amdgcn_mfma_f32_16x16x16f16(a, whh1[0][kt & 3], ah[0], 0, 0, 0);
        ah[1] = __builtin_amdgcn_mfma_f32_16x16x16f16(a, whh1[1][kt & 3], ah[1], 0, 0, 0);
        ah[2] = __builtin_amdgcn_mfma_f32_16x16x16f16(a, whh1[2][kt & 3], ah[2], 0, 0, 0);
      }
#pragma unroll
      for (int nt = 0; nt < 3; ++nt) {
        const int g = (wave * 3 + nt) * 16 + col;
#pragma unroll
        for (int i = 0; i < 4; ++i) {
          const int m = quad * 4 + i;
          xg[m * G3 + g] = ax[nt][i];
          hg[m * G3 + g] = ah[nt][i];
        }
      }
      __syncthreads();

      // ======== phase 4: layer1 gate math, write new h1 (hi/lo) ========
#pragma unroll
      for (int r = 0; r < 4; ++r) {
        const int s = sb + r * 4;
        const float hprev = (float)F1[s * FSTR + jj] + (float)F1[s * FSTR + 64 + jj];
        const float xr = xg[s * G3 + jj],       hr = hg[s * G3 + jj];
        const float xz = xg[s * G3 + 64 + jj],  hz = hg[s * G3 + 64 + jj];
        const float xn = xg[s * G3 + 128 + jj], hn = hg[s * G3 + 128 + jj];
        const float rg = sigm(xr + hr + bias[2 * G3 + jj] + bias[3 * G3 + jj]);
        const float zg = sigm(xz + hz + bias[2 * G3 + 64 + jj] + bias[3 * G3 + 64 + jj]);
        const float ng = tanh_f(xn + bias[2 * G3 + 128 + jj] + rg * (hn + bias[3 * G3 + 128 + jj]));
        const float hnew = (1.0f - zg) * ng + zg * hprev;
        const _Float16 hi = (_Float16)hnew;
        const _Float16 lo = (_Float16)(hnew - (float)hi);
        F1[s * FSTR + jj] = hi;
        F1[s * FSTR + 64 + jj] = lo;
      }
      __syncthreads();
    }
  }

  // ======== epilogue: out = h1_last @ fcW^T + fcb ========
  if (tid < SPB) {
    float sum = fcWs[HID];
    for (int j = 0; j < HID; ++j)
      sum += ((float)F1[tid * FSTR + j] + (float)F1[tid * FSTR + 64 + j]) * fcWs[j];
    out[s0 + tid] = sum;
  }
}

extern "C" void kernel_launch(void* const* d_in, const int* in_sizes, int n_in,
                              void* d_out, int out_size, void* d_ws, size_t ws_size,
                              hipStream_t stream) {
  (void)in_sizes; (void)n_in; (void)d_ws; (void)ws_size; (void)out_size;
  gru_fused<<<NBATCH / SPB, 256, 0, stream>>>(
      (const float*)d_in[0],  (const float*)d_in[1],
      (const float*)d_in[2],  (const float*)d_in[3],
      (const float*)d_in[4],  (const float*)d_in[5],
      (const float*)d_in[6],  (const float*)d_in[7],
      (const float*)d_in[8],  (const float*)d_in[9],
      (const float*)d_in[10],
      (float*)d_out);
}